// Round 5
// baseline (1318.864 us; speedup 1.0000x reference)
//
#include <hip/hip_runtime.h>
#include <hip/hip_bf16.h>
#include <stdint.h>

typedef unsigned short u16;
typedef unsigned int   u32;
typedef __attribute__((ext_vector_type(4))) float f32x4;
typedef __attribute__((ext_vector_type(2))) float f32x2;
typedef __attribute__((ext_vector_type(8))) short s16x8;

#define DEV __device__ __forceinline__

static constexpr int EDIM  = 1024;
static constexpr int MROWS = 8 * 48 * 48;   // 18432

DEV float b2f(u16 x) { u32 u = ((u32)x) << 16; float f; __builtin_memcpy(&f, &u, 4); return f; }
DEV u16 f2b(float f) {
    u32 u; __builtin_memcpy(&u, &f, 4);
    u32 r = (u + 0x7FFFu + ((u >> 16) & 1u)) >> 16;
    return (u16)r;
}

#define GLDS16(gsrc, ldst) __builtin_amdgcn_global_load_lds( \
    (const __attribute__((address_space(1))) u32*)(gsrc),    \
    (__attribute__((address_space(3))) u32*)(ldst), 16, 0, 0)

#define BAR()   __builtin_amdgcn_s_barrier()
#define LGKM0() asm volatile("s_waitcnt lgkmcnt(0)" ::: "memory")

// ===================== job descriptors (passed by value) ====================
enum { F_WRC = 1, F_PERM = 2, F_TANH = 4, F_SCORE = 8, F_OMAP1 = 16, F_OMAP2 = 32 };

struct GJob {
    const u16* A1; const u16* A2; const u16* Bt; const float* bias;
    u16* C; float* outF; const float* w2; float* score;
    int lda, lda2, ldc, KTOT, M, flags, tileEnd, pad;
};
struct GSet { int njobs, total; GJob j[2]; };

struct WJob { const float* src; u16* dst; int srcN, dstLd, kOff, nT, tileEnd, pad; };
struct WSet { int n, total; WJob j[11]; };

// ===================== weight convert (job-table) ===========================
__global__ void wconvJ_kernel(WSet ws) {
    int bid = blockIdx.x;
    int ji = 0;
    while (bid >= ws.j[ji].tileEnd) ++ji;
    int base = ji ? ws.j[ji - 1].tileEnd : 0;
    WJob J = ws.j[ji];
    int lt = bid - base;
    int n0 = (lt % J.nT) * 64, k0 = (lt / J.nT) * 64;
    __shared__ u16 tile[64][65];
    int tx = threadIdx.x & 63, ty = threadIdx.x >> 6;
#pragma unroll
    for (int i = 0; i < 16; ++i) {
        int r = ty * 16 + i;
        tile[r][tx] = f2b(J.src[(size_t)(k0 + r) * J.srcN + n0 + tx]);
    }
    __syncthreads();
#pragma unroll
    for (int i = 0; i < 16; ++i) {
        int r = ty * 16 + i;
        J.dst[(size_t)(n0 + r) * J.dstLd + J.kOff + k0 + tx] = tile[tx][r];
    }
}

// ===================== misc: casts, bias concat/fold, zero ==================
__global__ void misc_kernel(const float* WoCsrc, const float* WoRsrc,
                            u16* WoCnt, u16* WoRnt,
                            const float* bq_c, const float* bk_c, const float* bv_c, float* bqkvC,
                            const float* bq_r, const float* bk_r, const float* bv_r,
                            const float* bo_c, const u16* WqkvRT, float* bqkvR_eff,
                            const float* bo_r, const u16* WgaT, float* bgen_lin,
                            float* scores) {
    int id = blockIdx.x * 256 + threadIdx.x;
    const int C1 = 1024 * 1024 / 2;
    if (id < C1) {
        f32x2 v = *(const f32x2*)&WoCsrc[(size_t)id * 2];
        *(u32*)&WoCnt[(size_t)id * 2] = (u32)f2b(v.x) | ((u32)f2b(v.y) << 16);
        return;
    }
    id -= C1;
    if (id < C1) {
        f32x2 v = *(const f32x2*)&WoRsrc[(size_t)id * 2];
        *(u32*)&WoRnt[(size_t)id * 2] = (u32)f2b(v.x) | ((u32)f2b(v.y) << 16);
        return;
    }
    id -= C1;
    if (id < 3072) { bqkvC[id] = (id < 1024) ? bq_c[id] : (id < 2048) ? bk_c[id - 1024] : bv_c[id - 2048]; return; }
    id -= 3072;
    if (id < 2 * MROWS) { scores[id] = 0.f; return; }
    id -= 2 * MROWS;
    if (id < 3072) {
        float s = (id < 1024) ? bq_r[id] : (id < 2048) ? bk_r[id - 1024] : bv_r[id - 2048];
        float d = 0.f;
        const u16* row = &WqkvRT[(size_t)id * 1024];
        for (int e = 0; e < 1024; e += 8) {
            s16x8 v = *(const s16x8*)&row[e];
#pragma unroll
            for (int u = 0; u < 8; ++u) d += bo_c[e + u] * b2f((u16)v[u]);
        }
        bqkvR_eff[id] = s + d;
        return;
    }
    id -= 3072;
    if (id < 1024) {
        float d = 0.f;
        const u16* row = &WgaT[(size_t)id * 1024];
        for (int e = 0; e < 1024; e += 8) {
            s16x8 v = *(const s16x8*)&row[e];
#pragma unroll
            for (int u = 0; u < 8; ++u) d += bo_r[e + u] * b2f((u16)v[u]);
        }
        bgen_lin[id] = d;
    }
}

// ===================== gather emb f32 -> Xc bf16, (b,k,n) rows ==============
__global__ void gather_kernel(const float* __restrict__ emb, u16* __restrict__ Xc) {
    int gid = blockIdx.x * 256 + threadIdx.x;
    int r = gid >> 9, c2 = gid & 511;
    int b = r / 2304, k = (r / 48) % 48, n = r % 48;
    int src = (n * 48 + k) * 8 + b;
    f32x2 v = *(const f32x2*)&emb[(size_t)src * EDIM + c2 * 2];
    *(u32*)&Xc[(size_t)r * EDIM + c2 * 2] = (u32)f2b(v.x) | ((u32)f2b(v.y) << 16);
}

// ===================== persistent 256x256 GEMM, 4-phase, 1 bar/phase ========
DEV s16x8 ldsrd(const u16* lds, int r, int kk, int qq) {
    int gl = kk * 4 + qq;
    return *(const s16x8*)&lds[r * 64 + ((gl ^ (r & 7)) << 3)];
}
DEV void stageA_p(u16* lds, const u16* Ag, int lda, int m0, int ka, int h, int wv, int lane) {
#pragma unroll
    for (int i = 0; i < 2; ++i) {
        int blk = wv * 2 + i;
        int row0 = (h + 2 * (blk >> 3)) * 64 + (blk & 7) * 8;
        int rr = row0 + (lane >> 3);
        int gl = (lane & 7) ^ (rr & 7);
        GLDS16(Ag + (size_t)(m0 + rr) * lda + ka + gl * 8, lds + row0 * 64);
    }
}
DEV void stageB_p(u16* lds, const u16* Bg, int ldb, int n0, int kb, int h, int wv, int lane) {
#pragma unroll
    for (int i = 0; i < 2; ++i) {
        int blk = wv * 2 + i;
        int row0 = (blk >> 2) * 64 + h * 32 + (blk & 3) * 8;
        int rr = row0 + (lane >> 3);
        int gl = (lane & 7) ^ (rr & 7);
        GLDS16(Bg + (size_t)(n0 + rr) * ldb + kb + gl * 8, lds + row0 * 64);
    }
}

__global__ __launch_bounds__(512, 2) void gemmP_kernel(GSet js) {
    __shared__ u16 lA[2][256 * 64];
    __shared__ u16 lB[2][256 * 64];
    int tid = threadIdx.x, lane = tid & 63, wv = tid >> 6;
    int wm = wv >> 2, wn = wv & 3;
    int fr = lane & 15, qq = lane >> 4;
    int G = gridDim.x;
    int tIdx = blockIdx.x;
    if (tIdx >= js.total) return;

    int cm0, cn0, cNT, cji, nm0, nn0, nNT, nji;
    bool hasN;
    auto resolve = [&](int ti, int& m0, int& n0, int& NT, int& ji) {
        int j = (js.njobs > 1 && ti >= js.j[0].tileEnd) ? 1 : 0;
        int lt = ti - (j ? js.j[0].tileEnd : 0);
        int mtl = js.j[j].M >> 8;
        m0 = (lt % mtl) * 256; n0 = (lt / mtl) * 256;
        NT = js.j[j].KTOT >> 6; ji = j;
    };
    resolve(tIdx, cm0, cn0, cNT, cji);
    int tN = tIdx + G;
    hasN = tN < js.total;
    if (hasN) resolve(tN, nm0, nn0, nNT, nji);

    auto stA = [&](int dstbuf, int td, int h) -> bool {
        const GJob* J; int m0, kk;
        if (td < cNT) { J = &js.j[cji]; m0 = cm0; kk = td * 64; }
        else { int u = td - cNT; if (!hasN || u >= nNT) return false;
               J = &js.j[nji]; m0 = nm0; kk = u * 64; }
        const u16* Ag = J->A1; int lda = J->lda;
        if (J->A2 && kk >= 1024) { Ag = J->A2; lda = J->lda2; kk -= 1024; }
        stageA_p(&lA[dstbuf][0], Ag, lda, m0, kk, h, wv, lane);
        return true;
    };
    auto stB = [&](int dstbuf, int td, int h) -> bool {
        const GJob* J; int n0, kk;
        if (td < cNT) { J = &js.j[cji]; n0 = cn0; kk = td * 64; }
        else { int u = td - cNT; if (!hasN || u >= nNT) return false;
               J = &js.j[nji]; n0 = nn0; kk = u * 64; }
        stageB_p(&lB[dstbuf][0], J->Bt, J->KTOT, n0, kk, h, wv, lane);
        return true;
    };

    f32x4 acc[8][4];
#pragma unroll
    for (int i = 0; i < 8; ++i)
#pragma unroll
        for (int jj = 0; jj < 4; ++jj) acc[i][jj] = (f32x4)0.f;

    stA(0, 0, 0); stA(0, 0, 1); stB(0, 0, 0); stB(0, 0, 1);
    stA(1, 1, 0); stB(1, 1, 0); stB(1, 1, 1);
    asm volatile("s_waitcnt vmcnt(6)" ::: "memory");
    BAR();

    s16x8 A8[8], B0[4], B1[4];
    int buf = 0, t = 0;
    for (;;) {
        const u16* lAb = &lA[buf][0];
        const u16* lBb = &lB[buf][0];

        // phase 0
#pragma unroll
        for (int m = 0; m < 4; ++m)
#pragma unroll
            for (int kk = 0; kk < 2; ++kk)
                A8[m * 2 + kk] = ldsrd(lAb, wm * 128 + m * 16 + fr, kk, qq);
#pragma unroll
        for (int n = 0; n < 2; ++n)
#pragma unroll
            for (int kk = 0; kk < 2; ++kk)
                B0[n * 2 + kk] = ldsrd(lBb, wn * 64 + n * 16 + fr, kk, qq);
        bool h1ex = stA(buf ^ 1, t + 1, 1);
        LGKM0();
        __builtin_amdgcn_s_setprio(1);
#pragma unroll
        for (int m = 0; m < 4; ++m)
#pragma unroll
            for (int n = 0; n < 2; ++n)
#pragma unroll
                for (int kk = 0; kk < 2; ++kk)
                    acc[m][n] = __builtin_amdgcn_mfma_f32_16x16x32_bf16(
                        A8[m * 2 + kk], B0[n * 2 + kk], acc[m][n], 0, 0, 0);
        __builtin_amdgcn_s_setprio(0);
        BAR();

        // phase 1
#pragma unroll
        for (int n = 0; n < 2; ++n)
#pragma unroll
            for (int kk = 0; kk < 2; ++kk)
                B1[n * 2 + kk] = ldsrd(lBb, wn * 64 + 32 + n * 16 + fr, kk, qq);
        bool h2ex = stA(buf, t + 2, 0);
        LGKM0();
        __builtin_amdgcn_s_setprio(1);
#pragma unroll
        for (int m = 0; m < 4; ++m)
#pragma unroll
            for (int n = 0; n < 2; ++n)
#pragma unroll
                for (int kk = 0; kk < 2; ++kk)
                    acc[m][n + 2] = __builtin_amdgcn_mfma_f32_16x16x32_bf16(
                        A8[m * 2 + kk], B1[n * 2 + kk], acc[m][n + 2], 0, 0, 0);
        __builtin_amdgcn_s_setprio(0);
        BAR();

        // phase 2
#pragma unroll
        for (int m = 0; m < 4; ++m)
#pragma unroll
            for (int kk = 0; kk < 2; ++kk)
                A8[m * 2 + kk] = ldsrd(lAb, wm * 128 + 64 + m * 16 + fr, kk, qq);
        stB(buf, t + 2, 0);
        LGKM0();
        __builtin_amdgcn_s_setprio(1);
#pragma unroll
        for (int m = 0; m < 4; ++m)
#pragma unroll
            for (int n = 0; n < 2; ++n)
#pragma unroll
                for (int kk = 0; kk < 2; ++kk)
                    acc[m + 4][n] = __builtin_amdgcn_mfma_f32_16x16x32_bf16(
                        A8[m * 2 + kk], B0[n * 2 + kk], acc[m + 4][n], 0, 0, 0);
        __builtin_amdgcn_s_setprio(0);
        BAR();

        // phase 3
        stB(buf, t + 2, 1);
        __builtin_amdgcn_s_setprio(1);
#pragma unroll
        for (int m = 0; m < 4; ++m)
#pragma unroll
            for (int n = 0; n < 2; ++n)
#pragma unroll
                for (int kk = 0; kk < 2; ++kk)
                    acc[m + 4][n + 2] = __builtin_amdgcn_mfma_f32_16x16x32_bf16(
                        A8[m * 2 + kk], B1[n * 2 + kk], acc[m + 4][n + 2], 0, 0, 0);
        __builtin_amdgcn_s_setprio(0);
        if (h2ex)      asm volatile("s_waitcnt vmcnt(6)" ::: "memory");
        else if (h1ex) asm volatile("s_waitcnt vmcnt(0)" ::: "memory");
        BAR();

        buf ^= 1; ++t;
        if (t == cNT) {
            GJob J = js.j[cji];
            int crow4 = qq * 4;
#pragma unroll
            for (int mf = 0; mf < 8; ++mf) {
#pragma unroll
                for (int jj = 0; jj < 4; ++jj) {
                    int row = cm0 + wm * 128 + mf * 16 + crow4 + jj;
                    int orow = row, o32 = 0;
                    if (J.flags & (F_PERM | F_OMAP1)) {
                        int b = row / 2304, k = (row / 48) % 48, n = row % 48;
                        if (J.flags & F_PERM)  orow = (b * 48 + n) * 48 + k;
                        if (J.flags & F_OMAP1) o32 = k * 384 + b * 48 + n;
                    }
                    if (J.flags & F_OMAP2) {
                        int b = row / 2304, n = (row / 48) % 48, k = row % 48;
                        o32 = k * 384 + b * 48 + n;
                    }
                    float sc = 0.f;
#pragma unroll
                    for (int nf = 0; nf < 4; ++nf) {
                        int col = cn0 + wn * 64 + nf * 16 + fr;
                        float v = acc[mf][nf][jj];
                        if (J.bias) v += J.bias[col];
                        if (J.flags & F_TANH) v = tanhf(v);
                        if (J.flags & F_WRC) J.C[(size_t)orow * J.ldc + col] = f2b(v);
                        if (J.flags & (F_OMAP1 | F_OMAP2)) J.outF[(size_t)o32 * EDIM + col] = v;
                        if (J.flags & F_SCORE) sc += v * J.w2[col];
                    }
                    if (J.flags & F_SCORE) {
                        sc += __shfl_xor(sc, 1);
                        sc += __shfl_xor(sc, 2);
                        sc += __shfl_xor(sc, 4);
                        sc += __shfl_xor(sc, 8);
                        if (fr == 0) atomicAdd(&J.score[row], sc);
                    }
                }
            }
            if (!hasN) break;
#pragma unroll
            for (int i = 0; i < 8; ++i)
#pragma unroll
                for (int jj = 0; jj < 4; ++jj) acc[i][jj] = (f32x4)0.f;
            cm0 = nm0; cn0 = nn0; cNT = nNT; cji = nji;
            tN += G;
            hasN = tN < js.total;
            if (hasN) resolve(tN, nm0, nn0, nNT, nji);
            t = 0;
        }
    }
}

// ===================== attention ============================================
__global__ __launch_bounds__(64) void attn_kernel(u16* __restrict__ QKV) {
    __shared__ u16 lVt[128 * 72];
    __shared__ u16 lP[48 * 72];
    const int LDQ = 3072;
    int bb = blockIdx.x >> 3, h = blockIdx.x & 7;
    int lane = threadIdx.x;
    u16* Qp = QKV + (size_t)bb * 48 * LDQ + h * 128;
    const u16* Kp = Qp + 1024;
    const u16* Vp = Qp + 2048;

#pragma unroll
    for (int i = 0; i < 48; ++i) {
        u32 vv = *(const u32*)&Vp[(size_t)i * LDQ + lane * 2];
        lVt[(lane * 2) * 72 + i]     = (u16)(vv & 0xffffu);
        lVt[(lane * 2 + 1) * 72 + i] = (u16)(vv >> 16);
    }
    for (int i = lane; i < 128 * 16; i += 64) { int d = i >> 4, c = 48 + (i & 15); lVt[d * 72 + c] = 0; }
    for (int i = lane; i < 48 * 16; i += 64)  { int t = i >> 4, c = 48 + (i & 15); lP[t * 72 + c] = 0; }
    __syncthreads();

    int fr = lane & 15, fk = (lane >> 4) * 8, crow4 = (lane >> 4) * 4;
    f32x4 sc[3][3];
#pragma unroll
    for (int mf = 0; mf < 3; ++mf)
#pragma unroll
        for (int nf = 0; nf < 3; ++nf) sc[mf][nf] = (f32x4)0.f;

#pragma unroll
    for (int kk = 0; kk < 4; ++kk) {
        s16x8 aq[3], bk[3];
#pragma unroll
        for (int mf = 0; mf < 3; ++mf) aq[mf] = *(const s16x8*)&Qp[(size_t)(mf * 16 + fr) * LDQ + kk * 32 + fk];
#pragma unroll
        for (int nf = 0; nf < 3; ++nf) bk[nf] = *(const s16x8*)&Kp[(size_t)(nf * 16 + fr) * LDQ + kk * 32 + fk];
#pragma unroll
        for (int mf = 0; mf < 3; ++mf)
#pragma unroll
            for (int nf = 0; nf < 3; ++nf)
                sc[mf][nf] = __builtin_amdgcn_mfma_f32_16x16x32_bf16(aq[mf], bk[nf], sc[mf][nf], 0, 0, 0);
    }

    const float scale = 0.08838834764831845f;
#pragma unroll
    for (int mf = 0; mf < 3; ++mf) {
#pragma unroll
        for (int j = 0; j < 4; ++j) {
            float v0 = sc[mf][0][j] * scale;
            float v1 = sc[mf][1][j] * scale;
            float v2 = sc[mf][2][j] * scale;
            float mx = fmaxf(v0, fmaxf(v1, v2));
            mx = fmaxf(mx, __shfl_xor(mx, 1));
            mx = fmaxf(mx, __shfl_xor(mx, 2));
            mx = fmaxf(mx, __shfl_xor(mx, 4));
            mx = fmaxf(mx, __shfl_xor(mx, 8));
            float e0 = __expf(v0 - mx), e1 = __expf(v1 - mx), e2 = __expf(v2 - mx);
            float s = e0 + e1 + e2;
            s += __shfl_xor(s, 1);
            s += __shfl_xor(s, 2);
            s += __shfl_xor(s, 4);
            s += __shfl_xor(s, 8);
            float inv = 1.f / s;
            int t = mf * 16 + crow4 + j;
            lP[t * 72 + 0  + fr] = f2b(e0 * inv);
            lP[t * 72 + 16 + fr] = f2b(e1 * inv);
            lP[t * 72 + 32 + fr] = f2b(e2 * inv);
        }
    }
    __syncthreads();

    f32x4 o[3][8];
#pragma unroll
    for (int mf = 0; mf < 3; ++mf)
#pragma unroll
        for (int nf = 0; nf < 8; ++nf) o[mf][nf] = (f32x4)0.f;

#pragma unroll
    for (int kk = 0; kk < 2; ++kk) {
        s16x8 ap[3];
#pragma unroll
        for (int mf = 0; mf < 3; ++mf) ap[mf] = *(const s16x8*)&lP[(mf * 16 + fr) * 72 + kk * 32 + fk];
#pragma unroll
        for (int nf = 0; nf < 8; ++nf) {
            s16x8 bv = *(const s16x8*)&lVt[(nf * 16 + fr) * 72 + kk * 32 + fk];
#pragma unroll
            for (int mf = 0; mf < 3; ++mf)
                o[mf][nf] = __builtin_amdgcn_mfma_f32_16x16x32_bf16(ap[mf], bv, o[mf][nf], 0, 0, 0);
        }
    }
#pragma unroll
    for (int mf = 0; mf < 3; ++mf)
#pragma unroll
        for (int nf = 0; nf < 8; ++nf)
#pragma unroll
            for (int j = 0; j < 4; ++j) {
                int t = mf * 16 + crow4 + j, d = nf * 16 + fr;
                Qp[(size_t)t * LDQ + d] = f2b(o[mf][nf][j]);
            }
}

// ===================== combine + mean (fused) ===============================
__global__ void combine_mean_kernel(const u16* __restrict__ RDR, const u16* __restrict__ CDR,
                                    const float* __restrict__ srow, const float* __restrict__ scol,
                                    const float* __restrict__ emb, float* __restrict__ out) {
    int b = blockIdx.x / 48, n = blockIdx.x % 48;
    __shared__ float w0s[48], w1s[48];
    int tx = threadIdx.x;
    if (tx < 48) {
        int r2 = (b * 48 + n) * 48 + tx;
        float rs = srow[r2], cs = scol[r2];
        float m = fmaxf(rs, cs);
        float e0 = __expf(rs - m), e1 = __expf(cs - m);
        float inv = 1.f / (e0 + e1);
        w0s[tx] = e0 * inv; w1s[tx] = e1 * inv;
    }
    __syncthreads();
    float* out_mb = out + 393216;
    for (int e = tx; e < EDIM; e += 256) {
        float s = 0.f;
        for (int k = 0; k < 48; ++k) {
            size_t rb = (size_t)((b * 48 + n) * 48 + k) * EDIM;
            float rv = b2f(RDR[rb + e]);
            float cv = b2f(CDR[rb + e]);
            float hv = emb[((size_t)(n * 48 + k) * 8 + b) * EDIM + e];
            float v = w0s[k] * rv + w1s[k] * cv + hv;
            out_mb[(size_t)(k * 384 + b * 48 + n) * EDIM + e] = v;
            s += v;
        }
        out[(size_t)(n * 8 + b) * EDIM + e] = s * (1.f / 48.f);
    }
}

// ============================================================================
extern "C" void kernel_launch(void* const* d_in, const int* in_sizes, int n_in,
                              void* d_out, int out_size, void* d_ws, size_t ws_size,
                              hipStream_t stream) {
    const float* emb    = (const float*)d_in[0];
    const float* Wq_c   = (const float*)d_in[1];
    const float* bq_c   = (const float*)d_in[2];
    const float* Wk_c   = (const float*)d_in[3];
    const float* bk_c   = (const float*)d_in[4];
    const float* Wv_c   = (const float*)d_in[5];
    const float* bv_c   = (const float*)d_in[6];
    const float* Wo_c   = (const float*)d_in[7];
    const float* bo_c   = (const float*)d_in[8];
    const float* Wq_r   = (const float*)d_in[9];
    const float* bq_r   = (const float*)d_in[10];
    const float* Wk_r   = (const float*)d_in[11];
    const float* bk_r   = (const float*)d_in[12];
    const float* Wv_r   = (const float*)d_in[13];
    const float* bv_r   = (const float*)d_in[14];
    const float* Wo_r   = (const float*)d_in[15];
    const float* bo_r   = (const float*)d_in[16];
    const float* W_gen  = (const float*)d_in[17];
    const float* W_mlp1 = (const float*)d_in[18];
    const float* W_mlp2 = (const float*)d_in[19];
    (void)in_sizes; (void)n_in; (void)out_size; (void)ws_size;

    char* ws = (char*)d_ws;
    size_t off = 0;
    auto alloc = [&](size_t bytes) { char* p = ws + off; off += (bytes + 255) & ~(size_t)255; return p; };
    u16*   WqkvCT = (u16*)alloc((size_t)3072 * 1024 * 2);
    u16*   WqkvRT = (u16*)alloc((size_t)3072 * 1024 * 2);
    u16*   WoCT   = (u16*)alloc((size_t)1024 * 1024 * 2);
    u16*   WoRT   = (u16*)alloc((size_t)1024 * 1024 * 2);
    u16*   WoCnt  = (u16*)alloc((size_t)1024 * 1024 * 2);
    u16*   WoRnt  = (u16*)alloc((size_t)1024 * 1024 * 2);
    u16*   WgaT   = (u16*)alloc((size_t)1024 * 1024 * 2);
    u16*   BtGf   = (u16*)alloc((size_t)1024 * 2048 * 2);
    u16*   W1T    = (u16*)alloc((size_t)1024 * 2048 * 2);
    u16*   BtQKVr = (u16*)alloc((size_t)3072 * 1024 * 2);
    float* bqkvC  = (float*)alloc(3072 * 4);
    float* bqkvRe = (float*)alloc(3072 * 4);
    float* bgen   = (float*)alloc(1024 * 4);
    u16*   XA     = (u16*)alloc((size_t)MROWS * 1024 * 2);
    u16*   QKV    = (u16*)alloc((size_t)MROWS * 3072 * 2);
    u16*   QKV2   = (u16*)alloc((size_t)MROWS * 3072 * 2);
    u16*   CDR    = (u16*)alloc((size_t)MROWS * 1024 * 2);
    u16*   RDR    = (u16*)alloc((size_t)MROWS * 1024 * 2);
    float* score_row = (float*)alloc((size_t)MROWS * 4);
    float* score_col = (float*)alloc((size_t)MROWS * 4);

    float* out = (float*)d_out;
    float* out_col = out + 393216 + 18874368;
    float* out_row = out + 393216 + 2 * 18874368;

    dim3 tb(256), tb512(512);

    WSet wset = {};
    int te = 0;
    auto addW = [&](const float* src, u16* dst, int srcN, int dstLd, int kOff, int nT, int kT) {
        int i = wset.n++;
        te += nT * kT;
        WJob w = {src, dst, srcN, dstLd, kOff, nT, te, 0};
        wset.j[i] = w;
    };
    addW(Wq_c, WqkvCT,                   1024, 1024, 0, 16, 16);
    addW(Wk_c, WqkvCT + 1024 * 1024,     1024, 1024, 0, 16, 16);
    addW(Wv_c, WqkvCT + 2 * 1024 * 1024, 1024, 1024, 0, 16, 16);
    addW(Wo_c, WoCT,                     1024, 1024, 0, 16, 16);
    addW(Wq_r, WqkvRT,                   1024, 1024, 0, 16, 16);
    addW(Wk_r, WqkvRT + 1024 * 1024,     1024, 1024, 0, 16, 16);
    addW(Wv_r, WqkvRT + 2 * 1024 * 1024, 1024, 1024, 0, 16, 16);
    addW(Wo_r, WoRT,                     1024, 1024, 0, 16, 16);
    addW(W_gen,               WgaT,      1024, 1024, 0, 16, 16);
    addW(W_gen + 1024 * 1024, BtGf,      1024, 2048, 1024, 16, 16);
    addW(W_mlp1,              W1T,       1024, 2048, 0, 16, 32);
    wset.total = te;
    wconvJ_kernel<<<te, tb, 0, stream>>>(wset);

    int miscItems = 1024 * 1024 + 3072 + 2 * MROWS + 3072 + 1024;
    misc_kernel<<<(miscItems + 255) / 256, tb, 0, stream>>>(
        Wo_c, Wo_r, WoCnt, WoRnt,
        bq_c, bk_c, bv_c, bqkvC,
        bq_r, bk_r, bv_r,
        bo_c, WqkvRT, bqkvRe,
        bo_r, WgaT, bgen,
        score_row);

    gather_kernel<<<MROWS * 512 / 256, tb, 0, stream>>>(emb, XA);

    auto mkJob = [](const u16* A1, const u16* A2, const u16* Bt, const float* bias,
                    u16* C, float* outF, const float* w2, float* score,
                    int lda, int lda2, int ldc, int KTOT, int M, int flags) {
        GJob j = {A1, A2, Bt, bias, C, outF, w2, score, lda, lda2, ldc, KTOT, M, flags, 0, 0};
        return j;
    };
    auto run1 = [&](GJob a, int nA) {
        GSet gs = {};
        a.tileEnd = (a.M >> 8) * nA;
        gs.njobs = 1; gs.total = a.tileEnd; gs.j[0] = a;
        gemmP_kernel<<<256, tb512, 0, stream>>>(gs);
    };
    auto run2 = [&](GJob a, int nA, GJob b, int nB) {
        GSet gs = {};
        a.tileEnd = (a.M >> 8) * nA;
        b.tileEnd = a.tileEnd + (b.M >> 8) * nB;
        gs.njobs = 2; gs.total = b.tileEnd; gs.j[0] = a; gs.j[1] = b;
        gemmP_kernel<<<256, tb512, 0, stream>>>(gs);
    };

    // W-prep: BtQKVr[n][e] = sum_n1 Wqkv_r[n1][n] * Wo_c[e][n1]; BtGf[:, :1024] likewise
    run2(mkJob(WqkvRT, nullptr, WoCnt, nullptr, BtQKVr, nullptr, nullptr, nullptr,
               1024, 0, 1024, 1024, 3072, F_WRC), 4,
         mkJob(WgaT, nullptr, WoRnt, nullptr, BtGf, nullptr, nullptr, nullptr,
               1024, 0, 2048, 1024, 1024, F_WRC), 4);

    // D1: col QKV
    run1(mkJob(XA, nullptr, WqkvCT, bqkvC, QKV, nullptr, nullptr, nullptr,
               1024, 0, 3072, 1024, MROWS, F_WRC), 12);
    attn_kernel<<<384 * 8, 64, 0, stream>>>(QKV);
    // D2: CDR (+out_col) and fused QKV-row
    run2(mkJob(QKV, nullptr, WoCT, bo_c, CDR, out_col, nullptr, nullptr,
               3072, 0, 1024, 1024, MROWS, F_WRC | F_PERM | F_OMAP1), 4,
         mkJob(QKV, nullptr, BtQKVr, bqkvRe, QKV2, nullptr, nullptr, nullptr,
               3072, 0, 3072, 1024, MROWS, F_WRC | F_PERM), 12);
    attn_kernel<<<384 * 8, 64, 0, stream>>>(QKV2);
    // D3: RDR (+out_row) and GEN (fused Wo_r@Wg_a | Wg_b), GEN -> XA
    run2(mkJob(QKV2, nullptr, WoRT, bo_r, RDR, out_row, nullptr, nullptr,
               3072, 0, 1024, 1024, MROWS, F_WRC | F_OMAP2), 4,
         mkJob(QKV2, CDR, BtGf, bgen, XA, nullptr, nullptr, nullptr,
               3072, 1024, 1024, 2048, MROWS, F_WRC | F_TANH), 4);
    // D4: scores
    run2(mkJob(RDR, XA, W1T, nullptr, nullptr, nullptr, W_mlp2, score_row,
               1024, 1024, 1024, 2048, MROWS, F_SCORE | F_TANH), 4,
         mkJob(CDR, XA, W1T, nullptr, nullptr, nullptr, W_mlp2, score_col,
               1024, 1024, 1024, 2048, MROWS, F_SCORE | F_TANH), 4);

    combine_mean_kernel<<<384, tb, 0, stream>>>(RDR, CDR, score_row, score_col, emb, out);
}

// Round 6
// 1110.082 us; speedup vs baseline: 1.1881x; 1.1881x over previous
//
#include <hip/hip_runtime.h>
#include <hip/hip_bf16.h>
#include <stdint.h>

typedef unsigned short u16;
typedef unsigned int   u32;
typedef __attribute__((ext_vector_type(4))) float f32x4;
typedef __attribute__((ext_vector_type(2))) float f32x2;
typedef __attribute__((ext_vector_type(8))) short s16x8;

#define DEV __device__ __forceinline__

static constexpr int EDIM  = 1024;
static constexpr int MROWS = 8 * 48 * 48;   // 18432

DEV float b2f(u16 x) { u32 u = ((u32)x) << 16; float f; __builtin_memcpy(&f, &u, 4); return f; }
DEV u16 f2b(float f) {
    u32 u; __builtin_memcpy(&u, &f, 4);
    u32 r = (u + 0x7FFFu + ((u >> 16) & 1u)) >> 16;
    return (u16)r;
}

#define GLDS16(gsrc, ldst) __builtin_amdgcn_global_load_lds( \
    (const __attribute__((address_space(1))) u32*)(gsrc),    \
    (__attribute__((address_space(3))) u32*)(ldst), 16, 0, 0)

// ===================== job descriptors ======================================
enum { F_WRC = 1, F_PERM = 2, F_TANH = 4, F_SCORE = 8, F_OMAP1 = 16, F_OMAP2 = 32,
       F_OUTFLIN = 64, F_HGEN = 128 };

struct GJob {
    const u16* A1; const u16* A2; const u16* Bt; const float* bias;
    u16* C; float* outF; const float* w2; float* score;
    int lda, lda2, ldc, KTOT, M, flags, tileEnd, pad;
};
struct GSet3 { int njobs, pad; GJob j[3]; };

struct WJob { const float* src; u16* dst; int srcN, dstLd, kOff, nT, tileEnd, pad; };
struct WSet { int n, total; WJob j[12]; };

// ===================== weight convert (job-table) ===========================
__global__ void wconvJ_kernel(WSet ws) {
    int bid = blockIdx.x;
    int ji = 0;
    while (bid >= ws.j[ji].tileEnd) ++ji;
    int base = ji ? ws.j[ji - 1].tileEnd : 0;
    WJob J = ws.j[ji];
    int lt = bid - base;
    int n0 = (lt % J.nT) * 64, k0 = (lt / J.nT) * 64;
    __shared__ u16 tile[64][65];
    int tx = threadIdx.x & 63, ty = threadIdx.x >> 6;
#pragma unroll
    for (int i = 0; i < 16; ++i) {
        int r = ty * 16 + i;
        tile[r][tx] = f2b(J.src[(size_t)(k0 + r) * J.srcN + n0 + tx]);
    }
    __syncthreads();
#pragma unroll
    for (int i = 0; i < 16; ++i) {
        int r = ty * 16 + i;
        J.dst[(size_t)(n0 + r) * J.dstLd + J.kOff + k0 + tx] = tile[tx][r];
    }
}

// ===================== misc: casts, bias concat/fold, zero ==================
__global__ void misc_kernel(const float* WoCsrc, const float* WoRsrc,
                            u16* WoCnt, u16* WoRnt,
                            const float* bq_c, const float* bk_c, const float* bv_c, float* bqkvC,
                            const float* bq_r, const float* bk_r, const float* bv_r,
                            const float* bo_c, const u16* WqkvRT, float* bqkvR_eff,
                            const float* bo_r, const u16* WgaT, float* bgen_lin,
                            float* scores) {
    int id = blockIdx.x * 256 + threadIdx.x;
    const int C1 = 1024 * 1024 / 2;
    if (id < C1) {
        f32x2 v = *(const f32x2*)&WoCsrc[(size_t)id * 2];
        *(u32*)&WoCnt[(size_t)id * 2] = (u32)f2b(v.x) | ((u32)f2b(v.y) << 16);
        return;
    }
    id -= C1;
    if (id < C1) {
        f32x2 v = *(const f32x2*)&WoRsrc[(size_t)id * 2];
        *(u32*)&WoRnt[(size_t)id * 2] = (u32)f2b(v.x) | ((u32)f2b(v.y) << 16);
        return;
    }
    id -= C1;
    if (id < 3072) { bqkvC[id] = (id < 1024) ? bq_c[id] : (id < 2048) ? bk_c[id - 1024] : bv_c[id - 2048]; return; }
    id -= 3072;
    if (id < 2 * MROWS) { scores[id] = 0.f; return; }
    id -= 2 * MROWS;
    if (id < 3072) {
        float s = (id < 1024) ? bq_r[id] : (id < 2048) ? bk_r[id - 1024] : bv_r[id - 2048];
        float d = 0.f;
        const u16* row = &WqkvRT[(size_t)id * 1024];
        for (int e = 0; e < 1024; e += 8) {
            s16x8 v = *(const s16x8*)&row[e];
#pragma unroll
            for (int u = 0; u < 8; ++u) d += bo_c[e + u] * b2f((u16)v[u]);
        }
        bqkvR_eff[id] = s + d;
        return;
    }
    id -= 3072;
    if (id < 1024) {
        float d = 0.f;
        const u16* row = &WgaT[(size_t)id * 1024];
        for (int e = 0; e < 1024; e += 8) {
            s16x8 v = *(const s16x8*)&row[e];
#pragma unroll
            for (int u = 0; u < 8; ++u) d += bo_r[e + u] * b2f((u16)v[u]);
        }
        bgen_lin[id] = d;
    }
}

// ===================== gather emb f32 -> Xc bf16, (b,k,n) rows ==============
__global__ void gather_kernel(const float* __restrict__ emb, u16* __restrict__ Xc) {
    int gid = blockIdx.x * 256 + threadIdx.x;
    int r = gid >> 9, c2 = gid & 511;
    int b = r / 2304, k = (r / 48) % 48, n = r % 48;
    int src = (n * 48 + k) * 8 + b;
    f32x2 v = *(const f32x2*)&emb[(size_t)src * EDIM + c2 * 2];
    *(u32*)&Xc[(size_t)r * EDIM + c2 * 2] = (u32)f2b(v.x) | ((u32)f2b(v.y) << 16);
}

// ===================== 128x128 GEMM, BK=32, dbuf, job-table =================
// LDS tile [128][32] bf16 (64B rows = 4x16B granules); logical granule g of
// row r stored at phys slot (g+(r>>1))&3 — measured 0 bank conflicts (r2/r4).
__global__ __launch_bounds__(256, 4) void gemmJ_kernel(GSet3 js) {
    __shared__ u16 lA[2][128 * 32];
    __shared__ u16 lB[2][128 * 32];
    int bid = blockIdx.x;
    int ji = 0, base = 0;
    if (js.njobs > 1 && bid >= js.j[0].tileEnd) { ji = 1; base = js.j[0].tileEnd; }
    if (js.njobs > 2 && bid >= js.j[1].tileEnd) { ji = 2; base = js.j[1].tileEnd; }
    GJob J;
    if (ji == 0) J = js.j[0]; else if (ji == 1) J = js.j[1]; else J = js.j[2];

    int lt = bid - base;
    int mtl = J.M >> 7;
    int mt = lt % mtl, nt = lt / mtl;
    int m0 = mt * 128, n0 = nt * 128;
    int tid = threadIdx.x, lane = tid & 63, wv = tid >> 6;
    int wm = wv >> 1, wn = wv & 1;
    int fr = lane & 15, qq = lane >> 4;
    int NT = J.KTOT >> 5;

    f32x4 acc[4][4];
#pragma unroll
    for (int i = 0; i < 4; ++i)
#pragma unroll
        for (int jj = 0; jj < 4; ++jj) acc[i][jj] = (f32x4)0.f;

    auto STAGE = [&](int bsel, int kt) {
        int k0 = kt * 32;
        const u16* As = J.A1; int lda = J.lda; int ka = k0;
        if (J.A2 && k0 >= 1024) { As = J.A2; lda = J.lda2; ka = k0 - 1024; }
#pragma unroll
        for (int i = 0; i < 2; ++i) {
            int c = wv * 2 + i;
            int r = c * 16 + (lane >> 2);
            int qg = ((lane & 3) - (r >> 1)) & 3;
            GLDS16(As + (size_t)(m0 + r) * lda + ka + qg * 8, &lA[bsel][c * 512]);
            GLDS16(J.Bt + (size_t)(n0 + r) * J.KTOT + k0 + qg * 8, &lB[bsel][c * 512]);
        }
    };

    STAGE(0, 0);
    for (int kt = 0; kt < NT; ++kt) {
        __syncthreads();                    // drains vmcnt: buf[kt&1] ready
        if (kt + 1 < NT) STAGE((kt + 1) & 1, kt + 1);
        const u16* la = &lA[kt & 1][0];
        const u16* lb = &lB[kt & 1][0];
        s16x8 af[4], bf[4];
#pragma unroll
        for (int mf = 0; mf < 4; ++mf) {
            int rr = wm * 64 + mf * 16 + fr;
            af[mf] = *(const s16x8*)&la[rr * 32 + (((qq + (rr >> 1)) & 3) * 8)];
        }
#pragma unroll
        for (int nf = 0; nf < 4; ++nf) {
            int rn = wn * 64 + nf * 16 + fr;
            bf[nf] = *(const s16x8*)&lb[rn * 32 + (((qq + (rn >> 1)) & 3) * 8)];
        }
#pragma unroll
        for (int mf = 0; mf < 4; ++mf)
#pragma unroll
            for (int nf = 0; nf < 4; ++nf)
                acc[mf][nf] = __builtin_amdgcn_mfma_f32_16x16x32_bf16(af[mf], bf[nf], acc[mf][nf], 0, 0, 0);
    }

    // ---- epilogue ----
    int crow4 = qq * 4;
#pragma unroll
    for (int mf = 0; mf < 4; ++mf) {
#pragma unroll
        for (int jj = 0; jj < 4; ++jj) {
            int row = m0 + wm * 64 + mf * 16 + crow4 + jj;
            int orow = row, o32 = 0;
            if (J.flags & (F_PERM | F_OMAP1)) {   // rows (b,k,n)
                int b = row / 2304, k = (row / 48) % 48, n = row % 48;
                if (J.flags & F_PERM)  orow = (b * 48 + n) * 48 + k;
                if (J.flags & F_OMAP1) o32 = k * 384 + b * 48 + n;
            }
            if (J.flags & F_OMAP2) {              // rows (b,n,k)
                int b = row / 2304, n = (row / 48) % 48, k = row % 48;
                o32 = k * 384 + b * 48 + n;
            }
            float sc = 0.f;
#pragma unroll
            for (int nf = 0; nf < 4; ++nf) {
                int col = n0 + wn * 64 + nf * 16 + fr;
                float v = acc[mf][nf][jj];
                if (J.bias) v += J.bias[col];
                if (J.flags & F_HGEN) v += J.outF[(size_t)row * EDIM + col];
                if (J.flags & F_TANH) v = tanhf(v);
                if (J.flags & F_WRC) J.C[(size_t)orow * J.ldc + col] = f2b(v);
                if (J.flags & (F_OMAP1 | F_OMAP2)) J.outF[(size_t)o32 * EDIM + col] = v;
                if (J.flags & F_OUTFLIN) J.outF[(size_t)row * EDIM + col] = v;
                if (J.flags & F_SCORE) sc += v * J.w2[col];
            }
            if (J.flags & F_SCORE) {
                sc += __shfl_xor(sc, 1);
                sc += __shfl_xor(sc, 2);
                sc += __shfl_xor(sc, 4);
                sc += __shfl_xor(sc, 8);
                if (fr == 0) atomicAdd(&J.score[row], sc);
            }
        }
    }
}

// ===================== attention: 48x48, dh=128, O in-place -> Q cols =======
__global__ __launch_bounds__(64) void attn_kernel(u16* __restrict__ QKV) {
    __shared__ u16 lVt[128 * 72];
    __shared__ u16 lP[48 * 72];
    const int LDQ = 3072;
    int bb = blockIdx.x >> 3, h = blockIdx.x & 7;
    int lane = threadIdx.x;
    u16* Qp = QKV + (size_t)bb * 48 * LDQ + h * 128;
    const u16* Kp = Qp + 1024;
    const u16* Vp = Qp + 2048;

#pragma unroll
    for (int i = 0; i < 48; ++i) {
        u32 vv = *(const u32*)&Vp[(size_t)i * LDQ + lane * 2];
        lVt[(lane * 2) * 72 + i]     = (u16)(vv & 0xffffu);
        lVt[(lane * 2 + 1) * 72 + i] = (u16)(vv >> 16);
    }
    for (int i = lane; i < 128 * 16; i += 64) { int d = i >> 4, c = 48 + (i & 15); lVt[d * 72 + c] = 0; }
    for (int i = lane; i < 48 * 16; i += 64)  { int t = i >> 4, c = 48 + (i & 15); lP[t * 72 + c] = 0; }
    __syncthreads();

    int fr = lane & 15, fk = (lane >> 4) * 8, crow4 = (lane >> 4) * 4;
    f32x4 sc[3][3];
#pragma unroll
    for (int mf = 0; mf < 3; ++mf)
#pragma unroll
        for (int nf = 0; nf < 3; ++nf) sc[mf][nf] = (f32x4)0.f;

#pragma unroll
    for (int kk = 0; kk < 4; ++kk) {
        s16x8 aq[3], bk[3];
#pragma unroll
        for (int mf = 0; mf < 3; ++mf) aq[mf] = *(const s16x8*)&Qp[(size_t)(mf * 16 + fr) * LDQ + kk * 32 + fk];
#pragma unroll
        for (int nf = 0; nf < 3; ++nf) bk[nf] = *(const s16x8*)&Kp[(size_t)(nf * 16 + fr) * LDQ + kk * 32 + fk];
#pragma unroll
        for (int mf = 0; mf < 3; ++mf)
#pragma unroll
            for (int nf = 0; nf < 3; ++nf)
                sc[mf][nf] = __builtin_amdgcn_mfma_f32_16x16x32_bf16(aq[mf], bk[nf], sc[mf][nf], 0, 0, 0);
    }

    const float scale = 0.08838834764831845f;
#pragma unroll
    for (int mf = 0; mf < 3; ++mf) {
#pragma unroll
        for (int j = 0; j < 4; ++j) {
            float v0 = sc[mf][0][j] * scale;
            float v1 = sc[mf][1][j] * scale;
            float v2 = sc[mf][2][j] * scale;
            float mx = fmaxf(v0, fmaxf(v1, v2));
            mx = fmaxf(mx, __shfl_xor(mx, 1));
            mx = fmaxf(mx, __shfl_xor(mx, 2));
            mx = fmaxf(mx, __shfl_xor(mx, 4));
            mx = fmaxf(mx, __shfl_xor(mx, 8));
            float e0 = __expf(v0 - mx), e1 = __expf(v1 - mx), e2 = __expf(v2 - mx);
            float s = e0 + e1 + e2;
            s += __shfl_xor(s, 1);
            s += __shfl_xor(s, 2);
            s += __shfl_xor(s, 4);
            s += __shfl_xor(s, 8);
            float inv = 1.f / s;
            int t = mf * 16 + crow4 + j;
            lP[t * 72 + 0  + fr] = f2b(e0 * inv);
            lP[t * 72 + 16 + fr] = f2b(e1 * inv);
            lP[t * 72 + 32 + fr] = f2b(e2 * inv);
        }
    }
    __syncthreads();

    f32x4 o[3][8];
#pragma unroll
    for (int mf = 0; mf < 3; ++mf)
#pragma unroll
        for (int nf = 0; nf < 8; ++nf) o[mf][nf] = (f32x4)0.f;

#pragma unroll
    for (int kk = 0; kk < 2; ++kk) {
        s16x8 ap[3];
#pragma unroll
        for (int mf = 0; mf < 3; ++mf) ap[mf] = *(const s16x8*)&lP[(mf * 16 + fr) * 72 + kk * 32 + fk];
#pragma unroll
        for (int nf = 0; nf < 8; ++nf) {
            s16x8 bv = *(const s16x8*)&lVt[(nf * 16 + fr) * 72 + kk * 32 + fk];
#pragma unroll
            for (int mf = 0; mf < 3; ++mf)
                o[mf][nf] = __builtin_amdgcn_mfma_f32_16x16x32_bf16(ap[mf], bv, o[mf][nf], 0, 0, 0);
        }
    }
#pragma unroll
    for (int mf = 0; mf < 3; ++mf)
#pragma unroll
        for (int nf = 0; nf < 8; ++nf)
#pragma unroll
            for (int j = 0; j < 4; ++j) {
                int t = mf * 16 + crow4 + j, d = nf * 16 + fr;
                Qp[(size_t)t * LDQ + d] = f2b(o[mf][nf][j]);
            }
}

// ===================== combine + mean (fused) ===============================
__global__ void combine_mean_kernel(const u16* __restrict__ RDR, const u16* __restrict__ CDR,
                                    const float* __restrict__ srow, const float* __restrict__ scol,
                                    const float* __restrict__ emb, float* __restrict__ out) {
    int b = blockIdx.x / 48, n = blockIdx.x % 48;
    __shared__ float w0s[48], w1s[48];
    int tx = threadIdx.x;
    if (tx < 48) {
        int r2 = (b * 48 + n) * 48 + tx;
        float rs = srow[r2], cs = scol[r2];
        float m = fmaxf(rs, cs);
        float e0 = __expf(rs - m), e1 = __expf(cs - m);
        float inv = 1.f / (e0 + e1);
        w0s[tx] = e0 * inv; w1s[tx] = e1 * inv;
    }
    __syncthreads();
    float* out_mb = out + 393216;
    for (int e = tx; e < EDIM; e += 256) {
        float s = 0.f;
        for (int k = 0; k < 48; ++k) {
            size_t rb = (size_t)((b * 48 + n) * 48 + k) * EDIM;
            float rv = b2f(RDR[rb + e]);
            float cv = b2f(CDR[rb + e]);
            float hv = emb[((size_t)(n * 48 + k) * 8 + b) * EDIM + e];
            float v = w0s[k] * rv + w1s[k] * cv + hv;
            out_mb[(size_t)(k * 384 + b * 48 + n) * EDIM + e] = v;
            s += v;
        }
        out[(size_t)(n * 8 + b) * EDIM + e] = s * (1.f / 48.f);
    }
}

// ============================================================================
extern "C" void kernel_launch(void* const* d_in, const int* in_sizes, int n_in,
                              void* d_out, int out_size, void* d_ws, size_t ws_size,
                              hipStream_t stream) {
    const float* emb    = (const float*)d_in[0];
    const float* Wq_c   = (const float*)d_in[1];
    const float* bq_c   = (const float*)d_in[2];
    const float* Wk_c   = (const float*)d_in[3];
    const float* bk_c   = (const float*)d_in[4];
    const float* Wv_c   = (const float*)d_in[5];
    const float* bv_c   = (const float*)d_in[6];
    const float* Wo_c   = (const float*)d_in[7];
    const float* bo_c   = (const float*)d_in[8];
    const float* Wq_r   = (const float*)d_in[9];
    const float* bq_r   = (const float*)d_in[10];
    const float* Wk_r   = (const float*)d_in[11];
    const float* bk_r   = (const float*)d_in[12];
    const float* Wv_r   = (const float*)d_in[13];
    const float* bv_r   = (const float*)d_in[14];
    const float* Wo_r   = (const float*)d_in[15];
    const float* bo_r   = (const float*)d_in[16];
    const float* W_gen  = (const float*)d_in[17];
    const float* W_mlp1 = (const float*)d_in[18];
    const float* W_mlp2 = (const float*)d_in[19];
    (void)in_sizes; (void)n_in; (void)out_size; (void)ws_size;

    char* ws = (char*)d_ws;
    size_t off = 0;
    auto alloc = [&](size_t bytes) { char* p = ws + off; off += (bytes + 255) & ~(size_t)255; return p; };
    u16*   WqkvCT = (u16*)alloc((size_t)3072 * 1024 * 2);
    u16*   WqkvRT = (u16*)alloc((size_t)3072 * 1024 * 2);
    u16*   WoCT   = (u16*)alloc((size_t)1024 * 1024 * 2);
    u16*   WoRT   = (u16*)alloc((size_t)1024 * 1024 * 2);
    u16*   WoCnt  = (u16*)alloc((size_t)1024 * 1024 * 2);
    u16*   WoRnt  = (u16*)alloc((size_t)1024 * 1024 * 2);
    u16*   WgaT   = (u16*)alloc((size_t)1024 * 1024 * 2);
    u16*   BtGf   = (u16*)alloc((size_t)1024 * 2048 * 2);
    u16*   W1aT   = (u16*)alloc((size_t)1024 * 1024 * 2);
    u16*   W1bT   = (u16*)alloc((size_t)1024 * 1024 * 2);
    u16*   BtQKVr = (u16*)alloc((size_t)3072 * 1024 * 2);
    float* bqkvC  = (float*)alloc(3072 * 4);
    float* bqkvRe = (float*)alloc(3072 * 4);
    float* bgen   = (float*)alloc(1024 * 4);
    u16*   XA     = (u16*)alloc((size_t)MROWS * 1024 * 2);  // gather input; later GEN
    u16*   QKV    = (u16*)alloc((size_t)MROWS * 3072 * 2);  // col QKV; later Hgen (f32 75.5MB < 113MB)
    u16*   QKV2   = (u16*)alloc((size_t)MROWS * 3072 * 2);  // row QKV
    u16*   CDR    = (u16*)alloc((size_t)MROWS * 1024 * 2);
    u16*   RDR    = (u16*)alloc((size_t)MROWS * 1024 * 2);
    float* score_row = (float*)alloc((size_t)MROWS * 4);
    float* score_col = (float*)alloc((size_t)MROWS * 4);
    float* Hgen = (float*)QKV;   // reuse: QKV dead after D2

    float* out = (float*)d_out;
    float* out_col = out + 393216 + 18874368;
    float* out_row = out + 393216 + 2 * 18874368;

    dim3 tb(256);

    WSet wset = {};
    int te = 0;
    auto addW = [&](const float* src, u16* dst, int srcN, int dstLd, int kOff, int nT, int kT) {
        int i = wset.n++;
        te += nT * kT;
        WJob w = {src, dst, srcN, dstLd, kOff, nT, te, 0};
        wset.j[i] = w;
    };
    addW(Wq_c, WqkvCT,                   1024, 1024, 0, 16, 16);
    addW(Wk_c, WqkvCT + 1024 * 1024,     1024, 1024, 0, 16, 16);
    addW(Wv_c, WqkvCT + 2 * 1024 * 1024, 1024, 1024, 0, 16, 16);
    addW(Wo_c, WoCT,                     1024, 1024, 0, 16, 16);
    addW(Wq_r, WqkvRT,                   1024, 1024, 0, 16, 16);
    addW(Wk_r, WqkvRT + 1024 * 1024,     1024, 1024, 0, 16, 16);
    addW(Wv_r, WqkvRT + 2 * 1024 * 1024, 1024, 1024, 0, 16, 16);
    addW(Wo_r, WoRT,                     1024, 1024, 0, 16, 16);
    addW(W_gen,               WgaT,      1024, 1024, 0, 16, 16);
    addW(W_gen + 1024 * 1024, BtGf,      1024, 2048, 1024, 16, 16);
    addW(W_mlp1,               W1aT,     1024, 1024, 0, 16, 16);
    addW(W_mlp1 + 1024 * 1024, W1bT,     1024, 1024, 0, 16, 16);
    wset.total = te;
    wconvJ_kernel<<<te, tb, 0, stream>>>(wset);

    int miscItems = 1024 * 1024 + 3072 + 2 * MROWS + 3072 + 1024;
    misc_kernel<<<(miscItems + 255) / 256, tb, 0, stream>>>(
        Wo_c, Wo_r, WoCnt, WoRnt,
        bq_c, bk_c, bv_c, bqkvC,
        bq_r, bk_r, bv_r,
        bo_c, WqkvRT, bqkvRe,
        bo_r, WgaT, bgen,
        score_row);

    gather_kernel<<<MROWS * 512 / 256, tb, 0, stream>>>(emb, XA);

    auto mkJob = [](const u16* A1, const u16* A2, const u16* Bt, const float* bias,
                    u16* C, float* outF, const float* w2, float* score,
                    int lda, int lda2, int ldc, int KTOT, int M, int flags) {
        GJob j = {A1, A2, Bt, bias, C, outF, w2, score, lda, lda2, ldc, KTOT, M, flags, 0, 0};
        return j;
    };
    auto runJ = [&](GJob a, int nA, const GJob* b, int nB, const GJob* c, int nC) {
        GSet3 gs = {};
        a.tileEnd = (a.M >> 7) * nA;
        gs.j[0] = a;
        int tot = a.tileEnd, nj = 1;
        if (b) {
            GJob jb = *b;
            jb.tileEnd = tot + (jb.M >> 7) * nB;
            tot = jb.tileEnd; gs.j[1] = jb; nj = 2;
        }
        if (c) {
            GJob jc = *c;
            jc.tileEnd = tot + (jc.M >> 7) * nC;
            tot = jc.tileEnd; gs.j[2] = jc; nj = 3;
        }
        gs.njobs = nj;
        gemmJ_kernel<<<tot, tb, 0, stream>>>(gs);
    };

    // D1: [col QKV (3456)] + [BtQKVr = WqkvR^T x WoC (192)] + [BtGf[:, :1024] (64)]
    {
        GJob b = mkJob(WqkvRT, nullptr, WoCnt, nullptr, BtQKVr, nullptr, nullptr, nullptr,
                       1024, 0, 1024, 1024, 3072, F_WRC);
        GJob c = mkJob(WgaT, nullptr, WoRnt, nullptr, BtGf, nullptr, nullptr, nullptr,
                       1024, 0, 2048, 1024, 1024, F_WRC);
        runJ(mkJob(XA, nullptr, WqkvCT, bqkvC, QKV, nullptr, nullptr, nullptr,
                   1024, 0, 3072, 1024, MROWS, F_WRC), 24, &b, 8, &c, 8);
    }
    attn_kernel<<<384 * 8, 64, 0, stream>>>(QKV);
    // D2: [CDR (+out_col), PERM] + [QKV2 = O_col @ fused, PERM]
    {
        GJob b = mkJob(QKV, nullptr, BtQKVr, bqkvRe, QKV2, nullptr, nullptr, nullptr,
                       3072, 0, 3072, 1024, MROWS, F_WRC | F_PERM);
        runJ(mkJob(QKV, nullptr, WoCT, bo_c, CDR, out_col, nullptr, nullptr,
                   3072, 0, 1024, 1024, MROWS, F_WRC | F_PERM | F_OMAP1), 8, &b, 24, nullptr, 0);
    }
    attn_kernel<<<384 * 8, 64, 0, stream>>>(QKV2);
    // D3: [RDR (+out_row)] + [GEN = tanh(O_row@fusedWgA | CDR@WgB + bgen) -> XA]
    {
        GJob b = mkJob(QKV2, CDR, BtGf, bgen, XA, nullptr, nullptr, nullptr,
                       3072, 1024, 1024, 2048, MROWS, F_WRC | F_TANH);
        runJ(mkJob(QKV2, nullptr, WoRT, bo_r, RDR, out_row, nullptr, nullptr,
                   3072, 0, 1024, 1024, MROWS, F_WRC | F_OMAP2), 8, &b, 8, nullptr, 0);
    }
    // D4: Hgen = GEN @ W1b^T (f32, linear)  [QKV buffer reused]
    runJ(mkJob(XA, nullptr, W1bT, nullptr, nullptr, Hgen, nullptr, nullptr,
               1024, 0, 1024, 1024, MROWS, F_OUTFLIN), 8, nullptr, 0, nullptr, 0);
    // D5: scores = tanh(x@W1a + Hgen) . w2   (row, col)
    {
        GJob b = mkJob(CDR, nullptr, W1aT, nullptr, nullptr, Hgen, W_mlp2, score_col,
                       1024, 0, 1024, 1024, MROWS, F_SCORE | F_TANH | F_HGEN);
        runJ(mkJob(RDR, nullptr, W1aT, nullptr, nullptr, Hgen, W_mlp2, score_row,
                   1024, 0, 1024, 1024, MROWS, F_SCORE | F_TANH | F_HGEN), 8, &b, 8, nullptr, 0);
    }

    combine_mean_kernel<<<384, tb, 0, stream>>>(RDR, CDR, score_row, score_col, emb, out);
}